// Round 13
// baseline (424.575 us; speedup 1.0000x reference)
//
#include <hip/hip_runtime.h>
#include <math.h>
#include <stdint.h>
#include <stddef.h>

#define BB 4
#define SS 2048
#define DD 1024
#define HH 16
#define HD 64
#define UU 38
#define BH (BB*HH)        // 64
#define NROWS (BB*SS)     // 8192
#define QSZ (BB*HH*SS*HD) // 8388608 floats per Q/K/V
#define NSPLIT 16
#define SPLEN (SS/NSPLIT) // 128
#define QPAD 40

typedef unsigned short ushortT;
typedef unsigned int u32;
typedef __attribute__((ext_vector_type(8))) short bf16x8;
typedef __attribute__((ext_vector_type(4))) float f32x4;

static __device__ __forceinline__ ushortT f2bf(float f) {
  union { float f; unsigned int u; } v; v.f = f;
  unsigned int r = v.u + 0x7fffu + ((v.u >> 16) & 1u);  // round-to-nearest-even
  return (ushortT)(r >> 16);
}
static __device__ __forceinline__ float bf2f(ushortT h) {
  union { unsigned int u; float f; } v; v.u = ((unsigned int)h) << 16; return v.f;
}
// async global->LDS, 16B per lane; lds dest must be wave-uniform base (HW adds lane*16)
static __device__ __forceinline__ void gld16(const void* g, void* l) {
  __builtin_amdgcn_global_load_lds((const __attribute__((address_space(1))) u32*)g,
                                   (__attribute__((address_space(3))) u32*)l, 16, 0, 0);
}

// ---- x fp32 -> xh/xl bf16 (row-major, same layout) ----
__global__ __launch_bounds__(256) void split_x(
    const float* __restrict__ x, ushortT* __restrict__ xh, ushortT* __restrict__ xl)
{
  size_t i = ((size_t)blockIdx.x * 256 + threadIdx.x) * 8;
  float4 v0 = *(const float4*)&x[i];
  float4 v1 = *(const float4*)&x[i + 4];
  float fv[8] = {v0.x, v0.y, v0.z, v0.w, v1.x, v1.y, v1.z, v1.w};
  bf16x8 hv, lv;
#pragma unroll
  for (int j = 0; j < 8; ++j) {
    ushortT h = f2bf(fv[j]);
    hv[j] = (short)h;
    lv[j] = (short)f2bf(fv[j] - bf2f(h));
  }
  *(bf16x8*)&xh[i] = hv;
  *(bf16x8*)&xl[i] = lv;
}

// ---- W [K][N] fp32 -> W^T hi/lo bf16 [N][K]; z selects Wq/Wk/Wv ----
__global__ __launch_bounds__(256) void splitT_kernel(
    const float* __restrict__ Wq, const float* __restrict__ Wk, const float* __restrict__ Wv,
    ushortT* __restrict__ WqhT, ushortT* __restrict__ WqlT,
    ushortT* __restrict__ WkhT, ushortT* __restrict__ WklT,
    ushortT* __restrict__ WvhT, ushortT* __restrict__ WvlT)
{
  __shared__ float tile[64][65];
  const int z = blockIdx.z;
  const float* W = (z == 0) ? Wq : (z == 1) ? Wk : Wv;
  ushortT* WhT = (z == 0) ? WqhT : (z == 1) ? WkhT : WvhT;
  ushortT* WlT = (z == 0) ? WqlT : (z == 1) ? WklT : WvlT;
  const int t = threadIdx.x;
  const int bk = blockIdx.y * 64, bn = blockIdx.x * 64;
  const int rr = t >> 4, c4 = (t & 15) * 4;
#pragma unroll
  for (int p = 0; p < 4; ++p) {
    int row = rr + p * 16;
    float4 v = *(const float4*)&W[(size_t)(bk + row) * DD + bn + c4];
    tile[row][c4] = v.x; tile[row][c4+1] = v.y; tile[row][c4+2] = v.z; tile[row][c4+3] = v.w;
  }
  __syncthreads();
  const int n = t & 63, ks = (t >> 6) * 16;
  union { ushortT us[16]; uint4 q[2]; } hb, lb;
#pragma unroll
  for (int j = 0; j < 16; ++j) {
    float f = tile[ks + j][n];
    ushortT h = f2bf(f);
    hb.us[j] = h;
    lb.us[j] = f2bf(f - bf2f(h));
  }
  size_t o = ((size_t)(bn + n) * DD + (size_t)(bk + ks)) >> 3;
  ((uint4*)WhT)[o] = hb.q[0]; ((uint4*)WhT)[o + 1] = hb.q[1];
  ((uint4*)WlT)[o] = lb.q[0]; ((uint4*)WlT)[o + 1] = lb.q[1];
}

// ---- dedupe sample_idx -> unique list; also zero Vsum/Ksum accumulators ----
__global__ __launch_bounds__(256) void dedupe_kernel(
    const int* __restrict__ sidx, int* __restrict__ uidx, int* __restrict__ ucount,
    float* __restrict__ Vsum, float* __restrict__ Ksum)
{
  __shared__ unsigned bm[64];
  __shared__ int base[64];
  const int t = threadIdx.x;
  for (int i = t; i < BH * HD; i += 256) { Vsum[i] = 0.f; Ksum[i] = 0.f; }
  if (t < 64) bm[t] = 0;
  __syncthreads();
  for (int s = t; s < SS; s += 256) {
    int v = sidx[s];
    atomicOr(&bm[v >> 5], 1u << (v & 31));
  }
  __syncthreads();
  if (t < 64) {  // one full wave
    int c = __popc(bm[t]);
    int pre = c;
#pragma unroll
    for (int off = 1; off < 64; off <<= 1) {
      int o = __shfl_up(pre, off, 64);
      if (t >= off) pre += o;
    }
    base[t] = pre - c;
    if (t == 63) ucount[0] = pre;
  }
  __syncthreads();
  if (t < 64) {
    unsigned m = bm[t];
    int o = base[t];
    while (m) {
      int b = __ffs(m) - 1;
      uidx[o++] = t * 32 + b;
      m &= m - 1;
    }
  }
  __syncthreads();
  int total = ucount[0];
  int padded = (total + 127) & ~127;
  int first = uidx[0];
  for (int i = total + t; i < padded; i += 256) uidx[i] = first;
}

// ---- fused QKV projection GEMM: 256x128 tile, fine-phased pipeline ----
// grid 768 = 8 xcd x 4 m x 24 n. Phase = (tile, kk-half): 16 MFMA + stage 1
// A-half (2 gld16) + 1 B-half (1 gld16), 3-pair lead, vmcnt(6) per phase
// (T3+T4), setprio around MFMA (T5). Ring: 4 A-slots (16KB) + 4 B-slots (8KB).
// Q/K: 3-combo (NT=48). V: 2-combo (NT=32) + fused column-sum -> Vsum atomics.
__global__ __launch_bounds__(512) void gemm_qkv(
    const ushortT* __restrict__ Axh, const ushortT* __restrict__ Axl,
    const ushortT* __restrict__ WqhT, const ushortT* __restrict__ WqlT,
    const ushortT* __restrict__ WkhT, const ushortT* __restrict__ WklT,
    const ushortT* __restrict__ WvhT, const ushortT* __restrict__ WvlT,
    const float* __restrict__ bq, const float* __restrict__ bk, const float* __restrict__ bv,
    ushortT* __restrict__ Qhg, ushortT* __restrict__ Qlg,
    ushortT* __restrict__ Khg, ushortT* __restrict__ Klg,
    float* __restrict__ V, float* __restrict__ Vsum)
{
  __shared__ ushortT L[49152];               // 96KB: A 4x8192us, B 4x4096us
  const int t = threadIdx.x;
  const int lin = blockIdx.x;                // 768
  const int xcd = lin & 7;
  const int idx = lin >> 3;                  // 0..95
  const int m0 = (xcd * 4 + (idx & 3)) * 256;
  const int n_idx = idx >> 2;                // 0..23
  const int p = n_idx >> 3;                  // 0=Q 1=K 2=V
  const int n0 = (n_idx & 7) * 128;
  const ushortT* Bh = (p == 0) ? WqhT : (p == 1) ? WkhT : WvhT;
  const ushortT* Bl = (p == 0) ? WqlT : (p == 1) ? WklT : WvlT;
  const float* bias = (p == 0) ? bq : (p == 1) ? bk : bv;
  const int NTk = (p == 2) ? 32 : 48;
  const int NPH = NTk * 2;                   // phases = pairs
  const int lane = t & 63, wid = t >> 6;
  const int wrm = wid >> 1, wcn = wid & 1;   // 4M x 2N waves, 64x64 out each
  const int fr = lane & 15, fs = lane >> 4;
  const int wub = (t & ~63) * 8;             // wave-uniform dest (ushort units)

  f32x4 acc[4][4];
#pragma unroll
  for (int i = 0; i < 4; ++i)
#pragma unroll
    for (int j = 0; j < 4; ++j) acc[i][j] = (f32x4){0.f, 0.f, 0.f, 0.f};

  // stage pair P = (tile P>>1, kk P&1): A-half 256x32 (2 gld16) + B-half 128x32 (1)
  auto stage_pair = [&](int P) {
    const int TP = P >> 1, kk = P & 1;
    const int seg = TP >> 4;
    const int rk0 = (TP & 15) * 64 + kk * 32;
    const ushortT* a_src = (seg == 1) ? Axl : Axh;   // segments: hh, lh, hl
    const ushortT* b_src = (seg == 2) ? Bl : Bh;
    const int aslot = (P & 3) * 8192;
    const int bslot = 32768 + (P & 3) * 4096;
#pragma unroll
    for (int l = 0; l < 2; ++l) {
      int lu = l * 4096 + t * 8;             // lane's dest (ushort units)
      int row = lu >> 5;                     // 32 ushorts per row
      int chunk = (lu >> 3) & 3;
      int sch = chunk ^ ((row >> 2) & 3);    // inverse-swizzled source
      gld16(&a_src[(size_t)(m0 + row) * DD + rk0 + sch * 8],
            &L[aslot + l * 4096 + wub]);
    }
    {
      int row = t >> 2;                      // 0..127
      int chunk = t & 3;
      int sch = chunk ^ ((row >> 2) & 3);
      gld16(&b_src[(size_t)(n0 + row) * DD + rk0 + sch * 8],
            &L[bslot + wub]);
    }
  };
  auto compute = [&](int g) {                // 8 ds_read_b128 + 16 MFMA
    const int aslot = (g & 3) * 8192;
    const int bslot = 32768 + (g & 3) * 4096;
    bf16x8 a[4], b[4];
#pragma unroll
    for (int i = 0; i < 4; ++i) {
      int row = wrm * 64 + i * 16 + fr;
      a[i] = *(const bf16x8*)&L[aslot + row * 32 + ((fs ^ ((row >> 2) & 3)) * 8)];
    }
#pragma unroll
    for (int j = 0; j < 4; ++j) {
      int row = wcn * 64 + j * 16 + fr;
      b[j] = *(const bf16x8*)&L[bslot + row * 32 + ((fs ^ ((row >> 2) & 3)) * 8)];
    }
    __builtin_amdgcn_s_setprio(1);
#pragma unroll
    for (int i = 0; i < 4; ++i)
#pragma unroll
      for (int j = 0; j < 4; ++j)
        acc[i][j] = __builtin_amdgcn_mfma_f32_16x16x32_bf16(a[i], b[j], acc[i][j], 0, 0, 0);
    __builtin_amdgcn_s_setprio(0);
  };

  // prologue: 3 pairs in flight (9 loads); wait pair0 (outstanding = pairs 1,2 = 6)
  stage_pair(0); stage_pair(1); stage_pair(2);
  asm volatile("s_waitcnt vmcnt(6)" ::: "memory");
  __builtin_amdgcn_s_barrier();

  for (int g = 0; g < NPH; ++g) {
    if (g + 3 < NPH) stage_pair(g + 3);
    compute(g);
    if (g < NPH - 3) {
      asm volatile("s_waitcnt vmcnt(6)" ::: "memory");   // next pair ready; 2 in flight
      __builtin_amdgcn_s_barrier();
    } else if (g == NPH - 3) {
      asm volatile("s_waitcnt vmcnt(3)" ::: "memory");
      __builtin_amdgcn_s_barrier();
    } else if (g == NPH - 2) {
      asm volatile("s_waitcnt vmcnt(0)" ::: "memory");
      __builtin_amdgcn_s_barrier();
    }
  }

  // epilogue: C/D layout col=lane&15, row=(lane>>4)*4+r
  float csum[4] = {0.f, 0.f, 0.f, 0.f};
#pragma unroll
  for (int i = 0; i < 4; ++i) {
#pragma unroll
    for (int j = 0; j < 4; ++j) {
      int c = n0 + wcn * 64 + j * 16 + fr;
      float bs = bias[c];
      int h = c >> 6, hd = c & 63;
#pragma unroll
      for (int r = 0; r < 4; ++r) {
        int m = m0 + wrm * 64 + i * 16 + fs * 4 + r;
        int b = m >> 11, s = m & (SS - 1);
        size_t oidx = (((size_t)(b * HH + h)) * SS + s) * HD + hd;
        float val = acc[i][j][r] + bs;
        if (p == 2) {
          V[oidx] = val;
          csum[j] += val;
        } else {
          ushortT hv = f2bf(val);
          ushortT lv = f2bf(val - bf2f(hv));
          if (p == 0) { Qhg[oidx] = hv; Qlg[oidx] = lv; }
          else        { Khg[oidx] = hv; Klg[oidx] = lv; }
        }
      }
    }
  }
  if (p == 2) {  // block column-sum -> Vsum (256-row tile lies in one batch)
    __builtin_amdgcn_s_barrier();
    float* red = (float*)L;                  // [128 cols][16 slots]
    int slot = wrm * 4 + fs;
#pragma unroll
    for (int j = 0; j < 4; ++j)
      red[(wcn * 64 + j * 16 + fr) * 16 + slot] = csum[j];
    __syncthreads();
    if (t < 128) {
      float s = 0.f;
#pragma unroll
      for (int g = 0; g < 16; ++g) s += red[t * 16 + g];
      int c = n0 + t;
      int h = c >> 6, hd = c & 63;
      atomicAdd(&Vsum[((m0 >> 11) * HH + h) * HD + hd], s);
    }
  }
}

// ------------- per-(b,h) sum of sampled K rows -> Ksum (atomic) -------------
__global__ __launch_bounds__(256) void means_kernel(
    const ushortT* __restrict__ Khg, const ushortT* __restrict__ Klg,
    const int* __restrict__ sidx, float* __restrict__ Ksum)
{
  __shared__ float rk[4][64];
  const int bh = blockIdx.x;
  const int sp = blockIdx.y;      // 4 splits of 512 rows
  const int t = threadIdx.x;
  const int d = t & 63, pq = t >> 6;
  float ka = 0.f;
  const int r0 = sp * 512 + pq * 128;
  for (int r = r0; r < r0 + 128; ++r) {
    size_t ki = ((size_t)bh * SS + sidx[r]) * HD + d;
    ka += bf2f(Khg[ki]) + bf2f(Klg[ki]);
  }
  rk[pq][d] = ka;
  __syncthreads();
  if (t < 64)
    atomicAdd(&Ksum[bh * HD + t], rk[0][t] + rk[1][t] + rk[2][t] + rk[3][t]);
}

// --------- M[b,h,s] = (max_u Q.K[uidx[u]] - Q.Kmean) / 8, 3-combo MFMA ------
__global__ __launch_bounds__(256, 3) void m_mfma(
    const ushortT* __restrict__ Qhg, const ushortT* __restrict__ Qlg,
    const ushortT* __restrict__ Khg, const ushortT* __restrict__ Klg,
    const int* __restrict__ uidx, const int* __restrict__ ucount,
    const float* __restrict__ Ksum, float* __restrict__ M)
{
  __shared__ ushortT KhL[128 * 64], KlL[128 * 64];
  __shared__ float Mred[2][128];
  __shared__ float km[64];
  const int t = threadIdx.x;
  const int lin = blockIdx.x;                   // 1024 = 64 bh x 16 q-tiles
  const int swz = (lin & 7) * 128 + (lin >> 3);
  const int bh = swz >> 4;
  const int s0 = (swz & 15) * 128;
  const int lane = t & 63, w = t >> 6;
  const int wr = w >> 1, wc = w & 1;
  const int fr = lane & 15, fs = lane >> 4;
  if (t < 64) km[t] = Ksum[bh * HD + t] * (1.0f / SS);
  const int srow = t >> 3, sslot = t & 7;
  const int ntiles = (ucount[0] + 127) >> 7;
  const size_t qbase = (size_t)bh * SS + s0;
  float runmax[4][4];
#pragma unroll
  for (int i = 0; i < 4; ++i)
#pragma unroll
    for (int r = 0; r < 4; ++r) runmax[i][r] = -INFINITY;

  for (int ui = 0; ui < ntiles; ++ui) {
    __syncthreads();
#pragma unroll
    for (int is = 0; is < 4; ++is) {
      int row = is * 32 + srow;
      int gr = uidx[ui * 128 + row];
      int soff = ((sslot ^ (row & 7)) * 8);
      int cb = (is * 256 + (t & 192)) * 8;
      size_t ga = ((size_t)bh * SS + gr) * HD + soff;
      gld16(&Khg[ga], &KhL[cb]);
      gld16(&Klg[ga], &KlL[cb]);
    }
    __syncthreads();
    f32x4 acc[4][4];
#pragma unroll
    for (int i = 0; i < 4; ++i)
#pragma unroll
      for (int j = 0; j < 4; ++j) acc[i][j] = (f32x4){0.f, 0.f, 0.f, 0.f};
#pragma unroll
    for (int kk = 0; kk < 2; ++kk) {
      bf16x8 ah[4], al[4], bh[4], bl[4];
#pragma unroll
      for (int i = 0; i < 4; ++i) {
        size_t ga = (qbase + (size_t)(wr * 64 + i * 16 + fr)) * HD + kk * 32 + fs * 8;
        ah[i] = *(const bf16x8*)&Qhg[ga];
        al[i] = *(const bf16x8*)&Qlg[ga];
      }
#pragma unroll
      for (int j = 0; j < 4; ++j) {
        int row = wc * 64 + j * 16 + fr;
        int off = row * 64 + (((kk * 4 + fs) ^ (row & 7)) * 8);
        bh[j] = *(const bf16x8*)&KhL[off];
        bl[j] = *(const bf16x8*)&KlL[off];
      }
#pragma unroll
      for (int i = 0; i < 4; ++i)
#pragma unroll
        for (int j = 0; j < 4; ++j) {
          acc[i][j] = __builtin_amdgcn_mfma_f32_16x16x32_bf16(ah[i], bh[j], acc[i][j], 0, 0, 0);
          acc[i][j] = __builtin_amdgcn_mfma_f32_16x16x32_bf16(ah[i], bl[j], acc[i][j], 0, 0, 0);
          acc[i][j] = __builtin_amdgcn_mfma_f32_16x16x32_bf16(al[i], bh[j], acc[i][j], 0, 0, 0);
        }
    }
#pragma unroll
    for (int i = 0; i < 4; ++i)
#pragma unroll
      for (int j = 0; j < 4; ++j)
#pragma unroll
        for (int r = 0; r < 4; ++r) runmax[i][r] = fmaxf(runmax[i][r], acc[i][j][r]);
  }
#pragma unroll
  for (int i = 0; i < 4; ++i)
#pragma unroll
    for (int r = 0; r < 4; ++r) {
      float v = runmax[i][r];
      v = fmaxf(v, __shfl_xor(v, 1, 64));
      v = fmaxf(v, __shfl_xor(v, 2, 64));
      v = fmaxf(v, __shfl_xor(v, 4, 64));
      v = fmaxf(v, __shfl_xor(v, 8, 64));
      runmax[i][r] = v;
    }
  if (fr == 0) {
#pragma unroll
    for (int i = 0; i < 4; ++i)
#pragma unroll
      for (int r = 0; r < 4; ++r)
        Mred[wc][wr * 64 + i * 16 + fs * 4 + r] = runmax[i][r];
  }
  __syncthreads();
  if (t < 128) {
    float mx = fmaxf(Mred[0][t], Mred[1][t]);
    float md = 0.f;
    const ushortT* qh = &Qhg[(qbase + t) * HD];
    const ushortT* ql = &Qlg[(qbase + t) * HD];
#pragma unroll
    for (int k8 = 0; k8 < 8; ++k8) {
      bf16x8 hv = *(const bf16x8*)&qh[k8 * 8];
      bf16x8 lv = *(const bf16x8*)&ql[k8 * 8];
#pragma unroll
      for (int j = 0; j < 8; ++j)
        md += (bf2f((ushortT)hv[j]) + bf2f((ushortT)lv[j])) * km[k8 * 8 + j];
    }
    M[(size_t)bh * SS + s0 + t] = (mx - md) * 0.125f;
  }
}

// ------- top-38 per (b,h): register-resident + wave shfl reduce -------------
__global__ __launch_bounds__(256) void topk_kernel(const float* __restrict__ M,
                                                   int* __restrict__ topi)
{
  __shared__ float rw[4];
  __shared__ int   ri4[4];
  __shared__ int   winner;
  const int t = threadIdx.x, bh = blockIdx.x;
  const int lane = t & 63, w = t >> 6;
  float v[8];
#pragma unroll
  for (int j = 0; j < 8; ++j) v[j] = M[(size_t)bh * SS + t + j * 256];
  for (int it = 0; it < UU; ++it) {
    float bv = v[0]; int bj = 0;
#pragma unroll
    for (int j = 1; j < 8; ++j) if (v[j] > bv) { bv = v[j]; bj = j; }
    int bs = t + bj * 256;
#pragma unroll
    for (int off = 32; off > 0; off >>= 1) {
      float ov = __shfl_xor(bv, off, 64);
      int os = __shfl_xor(bs, off, 64);
      if (ov > bv || (ov == bv && os < bs)) { bv = ov; bs = os; }
    }
    if (lane == 0) { rw[w] = bv; ri4[w] = bs; }
    __syncthreads();
    if (t == 0) {
      float fv = rw[0]; int fsx = ri4[0];
#pragma unroll
      for (int g = 1; g < 4; ++g)
        if (rw[g] > fv || (rw[g] == fv && ri4[g] < fsx)) { fv = rw[g]; fsx = ri4[g]; }
      topi[bh * UU + it] = fsx;
      winner = fsx;
    }
    __syncthreads();
    int wi = winner;
    if ((wi & 255) == t) {
      int jj = wi >> 8;
#pragma unroll
      for (int j = 0; j < 8; ++j) if (j == jj) v[j] = -INFINITY;  // static index
    }
  }
}

// ---------- flash attention over selected queries, split over S -------------
__global__ __launch_bounds__(256) void attn_flash(
    const ushortT* __restrict__ Qhg, const ushortT* __restrict__ Qlg,
    const ushortT* __restrict__ Khg, const ushortT* __restrict__ Klg,
    const float* __restrict__ V, const int* __restrict__ topi,
    float* __restrict__ pacc, float* __restrict__ pm, float* __restrict__ pl)
{
  __shared__ float Qt[64][68];
  __shared__ float KV[64][68];
  __shared__ float Ps[64][68];
  __shared__ float redA[16][64];
  __shared__ float redB[16][64];
  __shared__ float mrow[64], lrow[64], scl[64];
  const int t  = threadIdx.x;
  const int bh = blockIdx.x;
  const int sp = blockIdx.y;
  const float* Vb = V + (size_t)bh * SS * HD;
  if (t < 64) { mrow[t] = -INFINITY; lrow[t] = 0.f; }
  {
    int q = t >> 2, k4 = (t & 3) * 16;
    float fv[16];
#pragma unroll
    for (int e = 0; e < 16; ++e) fv[e] = 0.f;
    if (q < UU) {
      int qidx = topi[bh * UU + q];
      size_t ga = ((size_t)bh * SS + qidx) * HD + k4;
      bf16x8 h0 = *(const bf16x8*)&Qhg[ga];
      bf16x8 h1 = *(const bf16x8*)&Qhg[ga + 8];
      bf16x8 l0 = *(const bf16x8*)&Qlg[ga];
      bf16x8 l1 = *(const bf16x8*)&Qlg[ga + 8];
#pragma unroll
      for (int j = 0; j < 8; ++j) {
        fv[j]     = bf2f((ushortT)h0[j]) + bf2f((ushortT)l0[j]);
        fv[8 + j] = bf2f((ushortT)h1[j]) + bf2f((ushortT)l1[j]);
      }
    }
#pragma unroll
    for (int e = 0; e < 16; ++e) Qt[k4 + e][q] = fv[e];
  }
  const int q4 = (t & 15) * 4, j4g = (t >> 4) * 4, d4 = (t >> 4) * 4;
  const int lj = t >> 2, lk4 = (t & 3) * 16;
  float acc[4][4] = {};
  for (int s0 = sp * SPLEN; s0 < (sp + 1) * SPLEN; s0 += 64) {
    __syncthreads();
    {  // stage K tile transposed, reconstructed from bf16 pair
      size_t ga = ((size_t)bh * SS + s0 + lj) * HD + lk4;
      bf16x8 h0 = *(const bf16x8*)&Khg[ga];
      bf16x8 h1 = *(const bf16x8*)&Khg[ga + 8];
      bf16x8 l0 = *(const bf16x8*)&Klg[ga];
      bf16x8 l1 = *(const bf16x8*)&Klg[ga + 8];
#pragma unroll
      for (int j = 0; j < 8; ++j) {
        KV[lk4 + j][lj]     = bf2f((ushortT)h0[j]) + bf2f((ushortT)l0[j]);
        KV[lk4 + 8 + j][lj] = bf2f((ushortT)h1[j]) + bf2f((ushortT)l1[j]);
      }
    }
    __syncthreads();
    float sacc[4][4] = {};
#pragma unroll 16
    for (int k = 0; k < 64; ++k) {
      float4 a = *(const float4*)&Qt[k][q4];
      float4 b = *(const float4*)&KV[k][j4g];
      sacc[0][0] += a.x*b.x; sacc[0][1] += a.x*b.y; sacc[0][2] += a.x*b.z; sacc[0][3] += a.x*b.w;
      sacc[1][0] += a.y*b.x; sacc[1][1] += a.y*b.y; sacc[1][2] += a.y*b.z; sacc[1][3] += a.y*b.w;
      sacc[2][0] += a.z*b.x; sacc[2][1] += a.z*b.y; sacc[2][2] += a.z*b.z; sacc[2][3] += a.z*b.w;
      sacc[3][0] += a.w*b.x; sacc[3][1] += a.w*b.y; sacc[3][2] += a.w*b.z; sacc[3][3] += a.w*b.w;
    }
#pragma unroll
    for (int i = 0; i < 4; ++i) {
      float mx = fmaxf(fmaxf(sacc[i][0], sacc[i][1]), fmaxf(sacc[i][2], sacc[i][3]));
      redA[t >> 4][q4 + i] = mx;
    }
    __syncthreads();
    if (t < 64) {
      float mx = redA[0][t];
#pragma unroll
      for (int g = 1; g < 16; ++g) mx = fmaxf(mx, redA[g][t]);
      float mn = fmaxf(mrow[t], mx * 0.125f);
      scl[t] = __expf(mrow[t] - mn);
      mrow[t] = mn;
    }
    __syncthreads();
    float4 vld[4];
#pragma unroll
    for (int i = 0; i < 4; ++i)
      vld[i] = *(const float4*)&Vb[(size_t)(s0 + lj) * HD + lk4 + 4 * i];
    float psum[4] = {};
#pragma unroll
    for (int i = 0; i < 4; ++i) {
#pragma unroll
      for (int j = 0; j < 4; ++j) {
        float e = __expf(sacc[i][j] * 0.125f - mrow[q4 + i]);
        Ps[j4g + j][q4 + i] = e;
        psum[i] += e;
      }
      redB[t >> 4][q4 + i] = psum[i];
    }
#pragma unroll
    for (int i = 0; i < 4; ++i)
      *(float4*)&KV[lj][lk4 + 4 * i] = vld[i];
    __syncthreads();
    if (t < 64) {
      float ts = redB[0][t];
#pragma unroll
      for (int g = 1; g < 16; ++g) ts += redB[g][t];
      lrow[t] = lrow[t] * scl[t] + ts;
    }
#pragma unroll
    for (int i = 0; i < 4; ++i) {
      float fsc = scl[q4 + i];
      acc[i][0] *= fsc; acc[i][1] *= fsc; acc[i][2] *= fsc; acc[i][3] *= fsc;
    }
#pragma unroll 16
    for (int j = 0; j < 64; ++j) {
      float4 a = *(const float4*)&Ps[j][q4];
      float4 b = *(const float4*)&KV[j][d4];
      acc[0][0] += a.x*b.x; acc[0][1] += a.x*b.y; acc[0][2] += a.x*b.z; acc[0][3] += a.x*b.w;
      acc[1][0] += a.y*b.x; acc[1][1] += a.y*b.y; acc[1][2] += a.y*b.z; acc[1][3] += a.y*b.w;
      acc[2][0] += a.z*b.x; acc[2][1] += a.z*b.y; acc[2][2] += a.z*b.z; acc[2][3] += a.z*b.w;
      acc[3][0] += a.w*b.x; acc[3][1] += a.w*b.y; acc[3][2] += a.w*b.z; acc[3][3] += a.w*b.w;
    }
  }
  const size_t pb = ((size_t)bh * NSPLIT + sp) * QPAD;
#pragma unroll
  for (int i = 0; i < 4; ++i) {
    int q = q4 + i;
    if (q < UU) {
#pragma unroll
      for (int j = 0; j < 4; ++j)
        pacc[(pb + q) * HD + d4 + j] = acc[i][j];
    }
  }
  if (t < UU) { pm[pb + t] = mrow[t]; pl[pb + t] = lrow[t]; }
}

// ---------- base[b,:] = (Vsum_flat[b,:]/SS) @ Wo + bo -----------------------
__global__ __launch_bounds__(256) void base_kernel(
    const float* __restrict__ Vsum, const float* __restrict__ Wo,
    const float* __restrict__ bo, float* __restrict__ base)
{
  __shared__ float red[16][BB][16];
  const int t = threadIdx.x;
  const int cl = t & 15, kg = t >> 4;
  const int c = blockIdx.x * 16 + cl;
  float acc[BB] = {};
  for (int k = kg * 64; k < kg * 64 + 64; ++k) {
    float w = Wo[(size_t)k * DD + c];
#pragma unroll
    for (int b = 0; b < BB; ++b) acc[b] += Vsum[b * DD + k] * w;
  }
#pragma unroll
  for (int b = 0; b < BB; ++b) red[kg][b][cl] = acc[b];
  __syncthreads();
  if (t < 64) {
    int b = t >> 4, cc = blockIdx.x * 16 + (t & 15);
    float s = 0.f;
#pragma unroll
    for (int g = 0; g < 16; ++g) s += red[g][b][t & 15];
    base[b * DD + cc] = s * (1.0f / SS) + bo[cc];
  }
}

__global__ void fill_kernel(const float* __restrict__ base, float* __restrict__ out)
{
  size_t i = (size_t)blockIdx.x * 256 + threadIdx.x;
  float4 bv = ((const float4*)base)[(i >> 19) * 256 + (i & 255)];
  ((float4*)out)[i] = bv;
}

// -- selected rows: combine split partials -> ctx, then out += (ctx-Vmean)@Wo_h --
__global__ __launch_bounds__(256) void scatter_kernel(
    const float* __restrict__ pacc, const float* __restrict__ pm,
    const float* __restrict__ pl, const float* __restrict__ Vsum,
    const int* __restrict__ topi, const float* __restrict__ Wo,
    float* __restrict__ out)
{
  __shared__ float delta[64];
  const int t  = threadIdx.x;
  const int bh = blockIdx.x;
  const int u  = blockIdx.y;
  const int b = bh >> 4, h = bh & 15;
  const int s = topi[bh * UU + u];
  if (t < 64) {
    float mv[NSPLIT];
    float ms = -INFINITY;
#pragma unroll
    for (int sp = 0; sp < NSPLIT; ++sp) {
      mv[sp] = pm[((size_t)bh * NSPLIT + sp) * QPAD + u];
      ms = fmaxf(ms, mv[sp]);
    }
    float l = 0.f, c = 0.f;
#pragma unroll
    for (int sp = 0; sp < NSPLIT; ++sp) {
      float wv = __expf(mv[sp] - ms);
      l += wv * pl[((size_t)bh * NSPLIT + sp) * QPAD + u];
      c += wv * pacc[(((size_t)bh * NSPLIT + sp) * QPAD + u) * HD + t];
    }
    delta[t] = c / l - Vsum[bh * HD + t] * (1.0f / SS);
  }
  __syncthreads();
  float* orow = out + ((size_t)b * SS + s) * DD;
#pragma unroll
  for (int j = 0; j < 4; ++j) {
    int c = t + j * 256;
    float acc = 0.f;
#pragma unroll 8
    for (int d = 0; d < 64; ++d) acc += delta[d] * Wo[(size_t)(h * HD + d) * DD + c];
    atomicAdd(&orow[c], acc);
  }
}

extern "C" void kernel_launch(void* const* d_in, const int* in_sizes, int n_in,
                              void* d_out, int out_size, void* d_ws, size_t ws_size,
                              hipStream_t stream) {
  const float* x  = (const float*)d_in[0];
  const float* Wq = (const float*)d_in[1];
  const float* bq = (const float*)d_in[2];
  const float* Wk = (const float*)d_in[3];
  const float* bk = (const float*)d_in[4];
  const float* Wv = (const float*)d_in[5];
  const float* bv = (const float*)d_in[6];
  const float* Wo = (const float*)d_in[7];
  const float* bo = (const float*)d_in[8];
  const int* sidx = (const int*)d_in[9];
  float* out = (float*)d_out;

  float* f     = (float*)d_ws;
  float* V     = f;                          // QSZ (fp32 V only)
  float* Ksum  = f + (size_t)QSZ;
  float* Vsum  = Ksum + BH * HD;
  float* Mbuf  = Vsum + BH * HD;
  float* base  = Mbuf + (size_t)BH * SS;
  float* ctx   = base + BB * DD;             // unused (layout stability)
  float* pacc  = ctx + (size_t)BH * UU * HD;
  float* pm    = pacc + (size_t)BH * NSPLIT * QPAD * HD;
  float* pl    = pm + (size_t)BH * NSPLIT * QPAD;
  int*   topi  = (int*)(pl + (size_t)BH * NSPLIT * QPAD);
  int*   uidx  = topi + 4096;
  int*   ucount= uidx + 4096;
  ushortT* usp = (ushortT*)(ucount + 64);
  ushortT* WqhT = usp;                          // DD*DD each
  ushortT* WqlT = WqhT + (size_t)DD * DD;
  ushortT* WkhT = WqlT + (size_t)DD * DD;
  ushortT* WklT = WkhT + (size_t)DD * DD;
  ushortT* WvhT = WklT + (size_t)DD * DD;
  ushortT* WvlT = WvhT + (size_t)DD * DD;
  ushortT* xh   = WvlT + (size_t)DD * DD;       // NROWS*DD
  ushortT* xl   = xh + (size_t)NROWS * DD;
  ushortT* Qhg  = xl + (size_t)NROWS * DD;      // QSZ
  ushortT* Qlg  = Qhg + (size_t)QSZ;
  ushortT* Khg  = Qlg + (size_t)QSZ;
  ushortT* Klg  = Khg + (size_t)QSZ;

  split_x<<<NROWS * DD / (256 * 8), 256, 0, stream>>>(x, xh, xl);
  splitT_kernel<<<dim3(16, 16, 3), 256, 0, stream>>>(Wq, Wk, Wv, WqhT, WqlT,
                                                     WkhT, WklT, WvhT, WvlT);
  dedupe_kernel<<<1, 256, 0, stream>>>(sidx, uidx, ucount, Vsum, Ksum);
  gemm_qkv<<<768, 512, 0, stream>>>(xh, xl, WqhT, WqlT, WkhT, WklT, WvhT, WvlT,
                                    bq, bk, bv, Qhg, Qlg, Khg, Klg, V, Vsum);
  means_kernel<<<dim3(BH, 4), 256, 0, stream>>>(Khg, Klg, sidx, Ksum);
  m_mfma<<<1024, 256, 0, stream>>>(Qhg, Qlg, Khg, Klg, uidx, ucount, Ksum, Mbuf);
  topk_kernel<<<BH, 256, 0, stream>>>(Mbuf, topi);
  attn_flash<<<dim3(BH, NSPLIT), 256, 0, stream>>>(Qhg, Qlg, Khg, Klg, V, topi, pacc, pm, pl);
  base_kernel<<<DD / 16, 256, 0, stream>>>(Vsum, Wo, bo, base);
  fill_kernel<<<(NROWS * DD / 4) / 256, 256, 0, stream>>>(base, out);
  scatter_kernel<<<dim3(BH, UU), 256, 0, stream>>>(pacc, pm, pl, Vsum, topi, Wo, out);
}

// Round 14
// 387.721 us; speedup vs baseline: 1.0951x; 1.0951x over previous
//
#include <hip/hip_runtime.h>
#include <math.h>
#include <stdint.h>
#include <stddef.h>

#define BB 4
#define SS 2048
#define DD 1024
#define HH 16
#define HD 64
#define UU 38
#define BH (BB*HH)        // 64
#define NROWS (BB*SS)     // 8192
#define QSZ (BB*HH*SS*HD) // 8388608 floats per Q/K/V
#define NSPLIT 16
#define SPLEN (SS/NSPLIT) // 128
#define QPAD 40

typedef unsigned short ushortT;
typedef unsigned int u32;
typedef __attribute__((ext_vector_type(8))) short bf16x8;
typedef __attribute__((ext_vector_type(4))) float f32x4;

static __device__ __forceinline__ ushortT f2bf(float f) {
  union { float f; unsigned int u; } v; v.f = f;
  unsigned int r = v.u + 0x7fffu + ((v.u >> 16) & 1u);  // round-to-nearest-even
  return (ushortT)(r >> 16);
}
static __device__ __forceinline__ float bf2f(ushortT h) {
  union { unsigned int u; float f; } v; v.u = ((unsigned int)h) << 16; return v.f;
}
// async global->LDS, 16B per lane; lds dest must be wave-uniform base (HW adds lane*16)
static __device__ __forceinline__ void gld16(const void* g, void* l) {
  __builtin_amdgcn_global_load_lds((const __attribute__((address_space(1))) u32*)g,
                                   (__attribute__((address_space(3))) u32*)l, 16, 0, 0);
}

// ---- x fp32 -> xh/xl bf16 (row-major, same layout) ----
__global__ __launch_bounds__(256) void split_x(
    const float* __restrict__ x, ushortT* __restrict__ xh, ushortT* __restrict__ xl)
{
  size_t i = ((size_t)blockIdx.x * 256 + threadIdx.x) * 8;
  float4 v0 = *(const float4*)&x[i];
  float4 v1 = *(const float4*)&x[i + 4];
  float fv[8] = {v0.x, v0.y, v0.z, v0.w, v1.x, v1.y, v1.z, v1.w};
  bf16x8 hv, lv;
#pragma unroll
  for (int j = 0; j < 8; ++j) {
    ushortT h = f2bf(fv[j]);
    hv[j] = (short)h;
    lv[j] = (short)f2bf(fv[j] - bf2f(h));
  }
  *(bf16x8*)&xh[i] = hv;
  *(bf16x8*)&xl[i] = lv;
}

// ---- W [K][N] fp32 -> W^T hi/lo bf16 [N][K]; z selects Wq/Wk/Wv ----
__global__ __launch_bounds__(256) void splitT_kernel(
    const float* __restrict__ Wq, const float* __restrict__ Wk, const float* __restrict__ Wv,
    ushortT* __restrict__ WqhT, ushortT* __restrict__ WqlT,
    ushortT* __restrict__ WkhT, ushortT* __restrict__ WklT,
    ushortT* __restrict__ WvhT, ushortT* __restrict__ WvlT)
{
  __shared__ float tile[64][65];
  const int z = blockIdx.z;
  const float* W = (z == 0) ? Wq : (z == 1) ? Wk : Wv;
  ushortT* WhT = (z == 0) ? WqhT : (z == 1) ? WkhT : WvhT;
  ushortT* WlT = (z == 0) ? WqlT : (z == 1) ? WklT : WvlT;
  const int t = threadIdx.x;
  const int bk = blockIdx.y * 64, bn = blockIdx.x * 64;
  const int rr = t >> 4, c4 = (t & 15) * 4;
#pragma unroll
  for (int p = 0; p < 4; ++p) {
    int row = rr + p * 16;
    float4 v = *(const float4*)&W[(size_t)(bk + row) * DD + bn + c4];
    tile[row][c4] = v.x; tile[row][c4+1] = v.y; tile[row][c4+2] = v.z; tile[row][c4+3] = v.w;
  }
  __syncthreads();
  const int n = t & 63, ks = (t >> 6) * 16;
  union { ushortT us[16]; uint4 q[2]; } hb, lb;
#pragma unroll
  for (int j = 0; j < 16; ++j) {
    float f = tile[ks + j][n];
    ushortT h = f2bf(f);
    hb.us[j] = h;
    lb.us[j] = f2bf(f - bf2f(h));
  }
  size_t o = ((size_t)(bn + n) * DD + (size_t)(bk + ks)) >> 3;
  ((uint4*)WhT)[o] = hb.q[0]; ((uint4*)WhT)[o + 1] = hb.q[1];
  ((uint4*)WlT)[o] = lb.q[0]; ((uint4*)WlT)[o + 1] = lb.q[1];
}

// ---- dedupe sample_idx -> unique list; also zero Vsum/Ksum accumulators ----
__global__ __launch_bounds__(256) void dedupe_kernel(
    const int* __restrict__ sidx, int* __restrict__ uidx, int* __restrict__ ucount,
    float* __restrict__ Vsum, float* __restrict__ Ksum)
{
  __shared__ unsigned bm[64];
  __shared__ int base[64];
  const int t = threadIdx.x;
  for (int i = t; i < BH * HD; i += 256) { Vsum[i] = 0.f; Ksum[i] = 0.f; }
  if (t < 64) bm[t] = 0;
  __syncthreads();
  for (int s = t; s < SS; s += 256) {
    int v = sidx[s];
    atomicOr(&bm[v >> 5], 1u << (v & 31));
  }
  __syncthreads();
  if (t < 64) {  // one full wave
    int c = __popc(bm[t]);
    int pre = c;
#pragma unroll
    for (int off = 1; off < 64; off <<= 1) {
      int o = __shfl_up(pre, off, 64);
      if (t >= off) pre += o;
    }
    base[t] = pre - c;
    if (t == 63) ucount[0] = pre;
  }
  __syncthreads();
  if (t < 64) {
    unsigned m = bm[t];
    int o = base[t];
    while (m) {
      int b = __ffs(m) - 1;
      uidx[o++] = t * 32 + b;
      m &= m - 1;
    }
  }
  __syncthreads();
  int total = ucount[0];
  int padded = (total + 127) & ~127;
  int first = uidx[0];
  for (int i = total + t; i < padded; i += 256) uidx[i] = first;
}

// ---- fused QKV projection GEMM, virtual-K, virtual-N=3072 ----
// grid 1536. XCD-local m-chunk (8 m-tiles/XCD, A set 4MB = L2).
// Q/K: 3-combo (NT=48). V: 2-combo (NT=32) + fused column-sum -> Vsum atomics.
__global__ __launch_bounds__(256, 4) void gemm_qkv(
    const ushortT* __restrict__ Axh, const ushortT* __restrict__ Axl,
    const ushortT* __restrict__ WqhT, const ushortT* __restrict__ WqlT,
    const ushortT* __restrict__ WkhT, const ushortT* __restrict__ WklT,
    const ushortT* __restrict__ WvhT, const ushortT* __restrict__ WvlT,
    const float* __restrict__ bq, const float* __restrict__ bk, const float* __restrict__ bv,
    ushortT* __restrict__ Qhg, ushortT* __restrict__ Qlg,
    ushortT* __restrict__ Khg, ushortT* __restrict__ Klg,
    float* __restrict__ V, float* __restrict__ Vsum)
{
  __shared__ ushortT As[128 * 64];
  __shared__ ushortT Bs[128 * 64];
  const int t = threadIdx.x;
  const int lin = blockIdx.x;                    // 1536
  const int xcd = lin & 7;                       // dispatch round-robins across XCDs
  const int idx = lin >> 3;                      // 0..191 within XCD
  const int m_loc = idx & 7;                     // m fastest within XCD
  const int n_idx = idx >> 3;                    // 0..23
  const int m0 = (xcd * 8 + m_loc) * 128;
  const int p = n_idx >> 3;                      // 0=Q 1=K 2=V
  const int n0 = (n_idx & 7) * 128;              // column base within this W
  const ushortT* Bh = (p == 0) ? WqhT : (p == 1) ? WkhT : WvhT;
  const ushortT* Bl = (p == 0) ? WqlT : (p == 1) ? WklT : WvlT;
  const float* bias = (p == 0) ? bq : (p == 1) ? bk : bv;
  const int NTk = (p == 2) ? 32 : 48;            // V: drop hl segment
  const int lane = t & 63, w = t >> 6;
  const int wr = w >> 1, wc = w & 1;
  const int fr = lane & 15, fs = lane >> 4;
  const int srow = t >> 3, sslot = t & 7;
  f32x4 acc[4][4];
#pragma unroll
  for (int i = 0; i < 4; ++i)
#pragma unroll
    for (int j = 0; j < 4; ++j) acc[i][j] = (f32x4){0.f, 0.f, 0.f, 0.f};

  for (int kt = 0; kt < NTk; ++kt) {
    const int seg = kt >> 4;
    const int rk0 = (kt & 15) * 64;
    const ushortT* a_src = (seg == 1) ? Axl : Axh;   // hh, lh, hl
    const ushortT* b_src = (seg == 2) ? Bl : Bh;
    __syncthreads();  // previous tile fully consumed
#pragma unroll
    for (int is = 0; is < 4; ++is) {
      int row = is * 32 + srow;
      int soff = ((sslot ^ (row & 7)) * 8);    // inverse-swizzled global source
      int cb = (is * 256 + (t & 192)) * 8;     // wave-uniform LDS chunk base
      gld16(&a_src[(size_t)(m0 + row) * DD + rk0 + soff], &As[cb]);
      gld16(&b_src[(size_t)(n0 + row) * DD + rk0 + soff], &Bs[cb]);
    }
    __syncthreads();  // drains vmcnt(0)
#pragma unroll
    for (int kk = 0; kk < 2; ++kk) {
      bf16x8 af[4], bf[4];
#pragma unroll
      for (int i = 0; i < 4; ++i) {
        int row = wr * 64 + i * 16 + fr;
        af[i] = *(const bf16x8*)&As[row * 64 + (((kk * 4 + fs) ^ (row & 7)) * 8)];
      }
#pragma unroll
      for (int j = 0; j < 4; ++j) {
        int row = wc * 64 + j * 16 + fr;
        bf[j] = *(const bf16x8*)&Bs[row * 64 + (((kk * 4 + fs) ^ (row & 7)) * 8)];
      }
#pragma unroll
      for (int i = 0; i < 4; ++i)
#pragma unroll
        for (int j = 0; j < 4; ++j)
          acc[i][j] = __builtin_amdgcn_mfma_f32_16x16x32_bf16(af[i], bf[j], acc[i][j], 0, 0, 0);
    }
  }
  // epilogue: C/D layout col=lane&15, row=(lane>>4)*4+r
  float csum[4] = {0.f, 0.f, 0.f, 0.f};
#pragma unroll
  for (int i = 0; i < 4; ++i) {
#pragma unroll
    for (int j = 0; j < 4; ++j) {
      int c = n0 + wc * 64 + j * 16 + fr;
      float bs = bias[c];
      int h = c >> 6, hd = c & 63;
#pragma unroll
      for (int r = 0; r < 4; ++r) {
        int m = m0 + wr * 64 + i * 16 + fs * 4 + r;
        int b = m >> 11, s = m & (SS - 1);
        size_t oidx = (((size_t)(b * HH + h)) * SS + s) * HD + hd;
        float val = acc[i][j][r] + bs;
        if (p == 2) {
          V[oidx] = val;
          csum[j] += val;
        } else {
          ushortT hv = f2bf(val);
          ushortT lv = f2bf(val - bf2f(hv));
          if (p == 0) { Qhg[oidx] = hv; Qlg[oidx] = lv; }
          else        { Khg[oidx] = hv; Klg[oidx] = lv; }
        }
      }
    }
  }
  if (p == 2) {  // block-level column-sum reduce -> Vsum (block rows lie in one b)
    __syncthreads();                 // all waves done reading As/Bs
    float* red = (float*)As;         // [128 cols][8 slots]
    int slot = wr * 4 + fs;
#pragma unroll
    for (int j = 0; j < 4; ++j)
      red[(wc * 64 + j * 16 + fr) * 8 + slot] = csum[j];
    __syncthreads();
    if (t < 128) {
      float s = 0.f;
#pragma unroll
      for (int g = 0; g < 8; ++g) s += red[t * 8 + g];
      int c = n0 + t;
      int h = c >> 6, hd = c & 63;
      atomicAdd(&Vsum[((m0 >> 11) * HH + h) * HD + hd], s);
    }
  }
}

// ------------- per-(b,h) sum of sampled K rows -> Ksum (atomic) -------------
__global__ __launch_bounds__(256) void means_kernel(
    const ushortT* __restrict__ Khg, const ushortT* __restrict__ Klg,
    const int* __restrict__ sidx, float* __restrict__ Ksum)
{
  __shared__ float rk[4][64];
  const int bh = blockIdx.x;
  const int sp = blockIdx.y;      // 4 splits of 512 rows
  const int t = threadIdx.x;
  const int d = t & 63, pq = t >> 6;
  float ka = 0.f;
  const int r0 = sp * 512 + pq * 128;
  for (int r = r0; r < r0 + 128; ++r) {
    size_t ki = ((size_t)bh * SS + sidx[r]) * HD + d;
    ka += bf2f(Khg[ki]) + bf2f(Klg[ki]);
  }
  rk[pq][d] = ka;
  __syncthreads();
  if (t < 64)
    atomicAdd(&Ksum[bh * HD + t], rk[0][t] + rk[1][t] + rk[2][t] + rk[3][t]);
}

// --------- M[b,h,s] = (max_u Q.K[uidx[u]] - Q.Kmean) / 8, 3-combo MFMA ------
// Q fragments read directly from global (per-wave-private, L2-hot); K-only LDS.
__global__ __launch_bounds__(256, 3) void m_mfma(
    const ushortT* __restrict__ Qhg, const ushortT* __restrict__ Qlg,
    const ushortT* __restrict__ Khg, const ushortT* __restrict__ Klg,
    const int* __restrict__ uidx, const int* __restrict__ ucount,
    const float* __restrict__ Ksum, float* __restrict__ M)
{
  __shared__ ushortT KhL[128 * 64], KlL[128 * 64];
  __shared__ float Mred[2][128];
  __shared__ float km[64];
  const int t = threadIdx.x;
  const int lin = blockIdx.x;                   // 1024 = 64 bh x 16 q-tiles
  const int swz = (lin & 7) * 128 + (lin >> 3); // 8 bh per XCD: K-gather L2-resident
  const int bh = swz >> 4;
  const int s0 = (swz & 15) * 128;
  const int lane = t & 63, w = t >> 6;
  const int wr = w >> 1, wc = w & 1;
  const int fr = lane & 15, fs = lane >> 4;
  if (t < 64) km[t] = Ksum[bh * HD + t] * (1.0f / SS);
  const int srow = t >> 3, sslot = t & 7;
  const int ntiles = (ucount[0] + 127) >> 7;
  const size_t qbase = (size_t)bh * SS + s0;
  float runmax[4][4];
#pragma unroll
  for (int i = 0; i < 4; ++i)
#pragma unroll
    for (int r = 0; r < 4; ++r) runmax[i][r] = -INFINITY;

  for (int ui = 0; ui < ntiles; ++ui) {
    __syncthreads();
#pragma unroll
    for (int is = 0; is < 4; ++is) {
      int row = is * 32 + srow;
      int gr = uidx[ui * 128 + row];
      int soff = ((sslot ^ (row & 7)) * 8);
      int cb = (is * 256 + (t & 192)) * 8;
      size_t ga = ((size_t)bh * SS + gr) * HD + soff;
      gld16(&Khg[ga], &KhL[cb]);
      gld16(&Klg[ga], &KlL[cb]);
    }
    __syncthreads();
    f32x4 acc[4][4];
#pragma unroll
    for (int i = 0; i < 4; ++i)
#pragma unroll
      for (int j = 0; j < 4; ++j) acc[i][j] = (f32x4){0.f, 0.f, 0.f, 0.f};
#pragma unroll
    for (int kk = 0; kk < 2; ++kk) {
      bf16x8 ah[4], al[4], bh[4], bl[4];
#pragma unroll
      for (int i = 0; i < 4; ++i) {
        size_t ga = (qbase + (size_t)(wr * 64 + i * 16 + fr)) * HD + kk * 32 + fs * 8;
        ah[i] = *(const bf16x8*)&Qhg[ga];
        al[i] = *(const bf16x8*)&Qlg[ga];
      }
#pragma unroll
      for (int j = 0; j < 4; ++j) {
        int row = wc * 64 + j * 16 + fr;
        int off = row * 64 + (((kk * 4 + fs) ^ (row & 7)) * 8);
        bh[j] = *(const bf16x8*)&KhL[off];
        bl[j] = *(const bf16x8*)&KlL[off];
      }
#pragma unroll
      for (int i = 0; i < 4; ++i)
#pragma unroll
        for (int j = 0; j < 4; ++j) {
          acc[i][j] = __builtin_amdgcn_mfma_f32_16x16x32_bf16(ah[i], bh[j], acc[i][j], 0, 0, 0);
          acc[i][j] = __builtin_amdgcn_mfma_f32_16x16x32_bf16(ah[i], bl[j], acc[i][j], 0, 0, 0);
          acc[i][j] = __builtin_amdgcn_mfma_f32_16x16x32_bf16(al[i], bh[j], acc[i][j], 0, 0, 0);
        }
    }
#pragma unroll
    for (int i = 0; i < 4; ++i)
#pragma unroll
      for (int j = 0; j < 4; ++j)
#pragma unroll
        for (int r = 0; r < 4; ++r) runmax[i][r] = fmaxf(runmax[i][r], acc[i][j][r]);
  }
#pragma unroll
  for (int i = 0; i < 4; ++i)
#pragma unroll
    for (int r = 0; r < 4; ++r) {
      float v = runmax[i][r];
      v = fmaxf(v, __shfl_xor(v, 1, 64));
      v = fmaxf(v, __shfl_xor(v, 2, 64));
      v = fmaxf(v, __shfl_xor(v, 4, 64));
      v = fmaxf(v, __shfl_xor(v, 8, 64));
      runmax[i][r] = v;
    }
  if (fr == 0) {
#pragma unroll
    for (int i = 0; i < 4; ++i)
#pragma unroll
      for (int r = 0; r < 4; ++r)
        Mred[wc][wr * 64 + i * 16 + fs * 4 + r] = runmax[i][r];
  }
  __syncthreads();
  if (t < 128) {
    float mx = fmaxf(Mred[0][t], Mred[1][t]);
    float md = 0.f;
    const ushortT* qh = &Qhg[(qbase + t) * HD];
    const ushortT* ql = &Qlg[(qbase + t) * HD];
#pragma unroll
    for (int k8 = 0; k8 < 8; ++k8) {
      bf16x8 hv = *(const bf16x8*)&qh[k8 * 8];
      bf16x8 lv = *(const bf16x8*)&ql[k8 * 8];
#pragma unroll
      for (int j = 0; j < 8; ++j)
        md += (bf2f((ushortT)hv[j]) + bf2f((ushortT)lv[j])) * km[k8 * 8 + j];
    }
    M[(size_t)bh * SS + s0 + t] = (mx - md) * 0.125f;
  }
}

// ------- top-38 per (b,h): register-resident + wave shfl reduce -------------
__global__ __launch_bounds__(256) void topk_kernel(const float* __restrict__ M,
                                                   int* __restrict__ topi)
{
  __shared__ float rw[4];
  __shared__ int   ri4[4];
  __shared__ int   winner;
  const int t = threadIdx.x, bh = blockIdx.x;
  const int lane = t & 63, w = t >> 6;
  float v[8];
#pragma unroll
  for (int j = 0; j < 8; ++j) v[j] = M[(size_t)bh * SS + t + j * 256];
  for (int it = 0; it < UU; ++it) {
    float bv = v[0]; int bj = 0;
#pragma unroll
    for (int j = 1; j < 8; ++j) if (v[j] > bv) { bv = v[j]; bj = j; }
    int bs = t + bj * 256;
#pragma unroll
    for (int off = 32; off > 0; off >>= 1) {
      float ov = __shfl_xor(bv, off, 64);
      int os = __shfl_xor(bs, off, 64);
      if (ov > bv || (ov == bv && os < bs)) { bv = ov; bs = os; }
    }
    if (lane == 0) { rw[w] = bv; ri4[w] = bs; }
    __syncthreads();
    if (t == 0) {
      float fv = rw[0]; int fsx = ri4[0];
#pragma unroll
      for (int g = 1; g < 4; ++g)
        if (rw[g] > fv || (rw[g] == fv && ri4[g] < fsx)) { fv = rw[g]; fsx = ri4[g]; }
      topi[bh * UU + it] = fsx;
      winner = fsx;
    }
    __syncthreads();
    int wi = winner;
    if ((wi & 255) == t) {
      int jj = wi >> 8;
#pragma unroll
      for (int j = 0; j < 8; ++j) if (j == jj) v[j] = -INFINITY;  // static index
    }
  }
}

// ---------- flash attention over selected queries, split over S -------------
__global__ __launch_bounds__(256) void attn_flash(
    const ushortT* __restrict__ Qhg, const ushortT* __restrict__ Qlg,
    const ushortT* __restrict__ Khg, const ushortT* __restrict__ Klg,
    const float* __restrict__ V, const int* __restrict__ topi,
    float* __restrict__ pacc, float* __restrict__ pm, float* __restrict__ pl)
{
  __shared__ float Qt[64][68];
  __shared__ float KV[64][68];
  __shared__ float Ps[64][68];
  __shared__ float redA[16][64];
  __shared__ float redB[16][64];
  __shared__ float mrow[64], lrow[64], scl[64];
  const int t  = threadIdx.x;
  const int bh = blockIdx.x;
  const int sp = blockIdx.y;
  const float* Vb = V + (size_t)bh * SS * HD;
  if (t < 64) { mrow[t] = -INFINITY; lrow[t] = 0.f; }
  {
    int q = t >> 2, k4 = (t & 3) * 16;
    float fv[16];
#pragma unroll
    for (int e = 0; e < 16; ++e) fv[e] = 0.f;
    if (q < UU) {
      int qidx = topi[bh * UU + q];
      size_t ga = ((size_t)bh * SS + qidx) * HD + k4;
      bf16x8 h0 = *(const bf16x8*)&Qhg[ga];
      bf16x8 h1 = *(const bf16x8*)&Qhg[ga + 8];
      bf16x8 l0 = *(const bf16x8*)&Qlg[ga];
      bf16x8 l1 = *(const bf16x8*)&Qlg[ga + 8];
#pragma unroll
      for (int j = 0; j < 8; ++j) {
        fv[j]     = bf2f((ushortT)h0[j]) + bf2f((ushortT)l0[j]);
        fv[8 + j] = bf2f((ushortT)h1[j]) + bf2f((ushortT)l1[j]);
      }
    }
#pragma unroll
    for (int e = 0; e < 16; ++e) Qt[k4 + e][q] = fv[e];
  }
  const int q4 = (t & 15) * 4, j4g = (t >> 4) * 4, d4 = (t >> 4) * 4;
  const int lj = t >> 2, lk4 = (t & 3) * 16;
  float acc[4][4] = {};
  for (int s0 = sp * SPLEN; s0 < (sp + 1) * SPLEN; s0 += 64) {
    __syncthreads();
    {  // stage K tile transposed, reconstructed from bf16 pair
      size_t ga = ((size_t)bh * SS + s0 + lj) * HD + lk4;
      bf16x8 h0 = *(const bf16x8*)&Khg[ga];
      bf16x8 h1 = *(const bf16x8*)&Khg[ga + 8];
      bf16x8 l0 = *(const bf16x8*)&Klg[ga];
      bf16x8 l1 = *(const bf16x8*)&Klg[ga + 8];
#pragma unroll
      for (int j = 0; j < 8; ++j) {
        KV[lk4 + j][lj]     = bf2f((ushortT)h0[j]) + bf2f((ushortT)l0[j]);
        KV[lk4 + 8 + j][lj] = bf2f((ushortT)h1[j]) + bf2f((ushortT)l1[j]);
      }
    }
    __syncthreads();
    float sacc[4][4] = {};
#pragma unroll 16
    for (int k = 0; k < 64; ++k) {
      float4 a = *(const float4*)&Qt[k][q4];
      float4 b = *(const float4*)&KV[k][j4g];
      sacc[0][0] += a.x*b.x; sacc[0][1] += a.x*b.y; sacc[0][2] += a.x*b.z; sacc[0][3] += a.x*b.w;
      sacc[1][0] += a.y*b.x; sacc[1][1] += a.y*b.y; sacc[1][2] += a.y*b.z; sacc[1][3] += a.y*b.w;
      sacc[2][0] += a.z*b.x; sacc[2][1] += a.z*b.y; sacc[2][2] += a.z*b.z; sacc[2][3] += a.z*b.w;
      sacc[3][0] += a.w*b.x; sacc[3][1] += a.w*b.y; sacc[3][2] += a.w*b.z; sacc[3][3] += a.w*b.w;
    }
#pragma unroll
    for (int i = 0; i < 4; ++i) {
      float mx = fmaxf(fmaxf(sacc[i][0], sacc[i][1]), fmaxf(sacc[i][2], sacc[i][3]));
      redA[t >> 4][q4 + i] = mx;
    }
    __syncthreads();
    if (t < 64) {
      float mx = redA[0][t];
#pragma unroll
      for (int g = 1; g < 16; ++g) mx = fmaxf(mx, redA[g][t]);
      float mn = fmaxf(mrow[t], mx * 0.125f);
      scl[t] = __expf(mrow[t] - mn);
      mrow[t] = mn;
    }
    __syncthreads();
    float4 vld[4];
#pragma unroll
    for (int i = 0; i < 4; ++i)
      vld[i] = *(const float4*)&Vb[(size_t)(s0 + lj) * HD + lk4 + 4 * i];
    float psum[4] = {};
#pragma unroll
    for (int i = 0; i < 4; ++i) {
#pragma unroll
      for (int j = 0; j < 4; ++j) {
        float e = __expf(sacc[i][j] * 0.125f - mrow[q4 + i]);
        Ps[j4g + j][q4 + i] = e;
        psum[i] += e;
      }
      redB[t >> 4][q4 + i] = psum[i];
    }
#pragma unroll
    for (int i = 0; i < 4; ++i)
      *(float4*)&KV[lj][lk4 + 4 * i] = vld[i];
    __syncthreads();
    if (t < 64) {
      float ts = redB[0][t];
#pragma unroll
      for (int g = 1; g < 16; ++g) ts += redB[g][t];
      lrow[t] = lrow[t] * scl[t] + ts;
    }
#pragma unroll
    for (int i = 0; i < 4; ++i) {
      float fsc = scl[q4 + i];
      acc[i][0] *= fsc; acc[i][1] *= fsc; acc[i][2] *= fsc; acc[i][3] *= fsc;
    }
#pragma unroll 16
    for (int j = 0; j < 64; ++j) {
      float4 a = *(const float4*)&Ps[j][q4];
      float4 b = *(const float4*)&KV[j][d4];
      acc[0][0] += a.x*b.x; acc[0][1] += a.x*b.y; acc[0][2] += a.x*b.z; acc[0][3] += a.x*b.w;
      acc[1][0] += a.y*b.x; acc[1][1] += a.y*b.y; acc[1][2] += a.y*b.z; acc[1][3] += a.y*b.w;
      acc[2][0] += a.z*b.x; acc[2][1] += a.z*b.y; acc[2][2] += a.z*b.z; acc[2][3] += a.z*b.w;
      acc[3][0] += a.w*b.x; acc[3][1] += a.w*b.y; acc[3][2] += a.w*b.z; acc[3][3] += a.w*b.w;
    }
  }
  const size_t pb = ((size_t)bh * NSPLIT + sp) * QPAD;
#pragma unroll
  for (int i = 0; i < 4; ++i) {
    int q = q4 + i;
    if (q < UU) {
#pragma unroll
      for (int j = 0; j < 4; ++j)
        pacc[(pb + q) * HD + d4 + j] = acc[i][j];
    }
  }
  if (t < UU) { pm[pb + t] = mrow[t]; pl[pb + t] = lrow[t]; }
}

// ---------- base[b,:] = (Vsum_flat[b,:]/SS) @ Wo + bo -----------------------
__global__ __launch_bounds__(256) void base_kernel(
    const float* __restrict__ Vsum, const float* __restrict__ Wo,
    const float* __restrict__ bo, float* __restrict__ base)
{
  __shared__ float red[16][BB][16];
  const int t = threadIdx.x;
  const int cl = t & 15, kg = t >> 4;
  const int c = blockIdx.x * 16 + cl;
  float acc[BB] = {};
  for (int k = kg * 64; k < kg * 64 + 64; ++k) {
    float w = Wo[(size_t)k * DD + c];
#pragma unroll
    for (int b = 0; b < BB; ++b) acc[b] += Vsum[b * DD + k] * w;
  }
#pragma unroll
  for (int b = 0; b < BB; ++b) red[kg][b][cl] = acc[b];
  __syncthreads();
  if (t < 64) {
    int b = t >> 4, cc = blockIdx.x * 16 + (t & 15);
    float s = 0.f;
#pragma unroll
    for (int g = 0; g < 16; ++g) s += red[g][b][t & 15];
    base[b * DD + cc] = s * (1.0f / SS) + bo[cc];
  }
}

__global__ void fill_kernel(const float* __restrict__ base, float* __restrict__ out)
{
  size_t i = (size_t)blockIdx.x * 256 + threadIdx.x;
  float4 bv = ((const float4*)base)[(i >> 19) * 256 + (i & 255)];
  ((float4*)out)[i] = bv;
}

// -- selected rows: combine split partials -> ctx, then out += (ctx-Vmean)@Wo_h --
__global__ __launch_bounds__(256) void scatter_kernel(
    const float* __restrict__ pacc, const float* __restrict__ pm,
    const float* __restrict__ pl, const float* __restrict__ Vsum,
    const int* __restrict__ topi, const float* __restrict__ Wo,
    float* __restrict__ out)
{
  __shared__ float delta[64];
  const int t  = threadIdx.x;
  const int bh = blockIdx.x;
  const int u  = blockIdx.y;
  const int b = bh >> 4, h = bh & 15;
  const int s = topi[bh * UU + u];
  if (t < 64) {
    float mv[NSPLIT];
    float ms = -INFINITY;
#pragma unroll
    for (int sp = 0; sp < NSPLIT; ++sp) {
      mv[sp] = pm[((size_t)bh * NSPLIT + sp) * QPAD + u];
      ms = fmaxf(ms, mv[sp]);
    }
    float l = 0.f, c = 0.f;
#pragma unroll
    for (int sp = 0; sp < NSPLIT; ++sp) {
      float wv = __expf(mv[sp] - ms);
      l += wv * pl[((size_t)bh * NSPLIT + sp) * QPAD + u];
      c += wv * pacc[(((size_t)bh * NSPLIT + sp) * QPAD + u) * HD + t];
    }
    delta[t] = c / l - Vsum[bh * HD + t] * (1.0f / SS);
  }
  __syncthreads();
  float* orow = out + ((size_t)b * SS + s) * DD;
#pragma unroll
  for (int j = 0; j < 4; ++j) {
    int c = t + j * 256;
    float acc = 0.f;
#pragma unroll 8
    for (int d = 0; d < 64; ++d) acc += delta[d] * Wo[(size_t)(h * HD + d) * DD + c];
    atomicAdd(&orow[c], acc);
  }
}

extern "C" void kernel_launch(void* const* d_in, const int* in_sizes, int n_in,
                              void* d_out, int out_size, void* d_ws, size_t ws_size,
                              hipStream_t stream) {
  const float* x  = (const float*)d_in[0];
  const float* Wq = (const float*)d_in[1];
  const float* bq = (const float*)d_in[2];
  const float* Wk = (const float*)d_in[3];
  const float* bk = (const float*)d_in[4];
  const float* Wv = (const float*)d_in[5];
  const float* bv = (const float*)d_in[6];
  const float* Wo = (const float*)d_in[7];
  const float* bo = (const float*)d_in[8];
  const int* sidx = (const int*)d_in[9];
  float* out = (float*)d_out;

  float* f     = (float*)d_ws;
  float* V     = f;                          // QSZ (fp32 V only)
  float* Ksum  = f + (size_t)QSZ;
  float* Vsum  = Ksum + BH * HD;
  float* Mbuf  = Vsum + BH * HD;
  float* base  = Mbuf + (size_t)BH * SS;
  float* ctx   = base + BB * DD;             // unused (layout stability)
  float* pacc  = ctx + (size_t)BH * UU * HD;
  float* pm    = pacc + (size_t)BH * NSPLIT * QPAD * HD;
  float* pl    = pm + (size_t)BH * NSPLIT * QPAD;
  int*   topi  = (int*)(pl + (size_t)BH * NSPLIT * QPAD);
  int*   uidx  = topi + 4096;
  int*   ucount= uidx + 4096;
  ushortT* usp = (ushortT*)(ucount + 64);
  ushortT* WqhT = usp;                          // DD*DD each
  ushortT* WqlT = WqhT + (size_t)DD * DD;
  ushortT* WkhT = WqlT + (size_t)DD * DD;
  ushortT* WklT = WkhT + (size_t)DD * DD;
  ushortT* WvhT = WklT + (size_t)DD * DD;
  ushortT* WvlT = WvhT + (size_t)DD * DD;
  ushortT* xh   = WvlT + (size_t)DD * DD;       // NROWS*DD
  ushortT* xl   = xh + (size_t)NROWS * DD;
  ushortT* Qhg  = xl + (size_t)NROWS * DD;      // QSZ
  ushortT* Qlg  = Qhg + (size_t)QSZ;
  ushortT* Khg  = Qlg + (size_t)QSZ;
  ushortT* Klg  = Khg + (size_t)QSZ;

  split_x<<<NROWS * DD / (256 * 8), 256, 0, stream>>>(x, xh, xl);
  splitT_kernel<<<dim3(16, 16, 3), 256, 0, stream>>>(Wq, Wk, Wv, WqhT, WqlT,
                                                     WkhT, WklT, WvhT, WvlT);
  dedupe_kernel<<<1, 256, 0, stream>>>(sidx, uidx, ucount, Vsum, Ksum);
  gemm_qkv<<<1536, 256, 0, stream>>>(xh, xl, WqhT, WqlT, WkhT, WklT, WvhT, WvlT,
                                     bq, bk, bv, Qhg, Qlg, Khg, Klg, V, Vsum);
  means_kernel<<<dim3(BH, 4), 256, 0, stream>>>(Khg, Klg, sidx, Ksum);
  m_mfma<<<1024, 256, 0, stream>>>(Qhg, Qlg, Khg, Klg, uidx, ucount, Ksum, Mbuf);
  topk_kernel<<<BH, 256, 0, stream>>>(Mbuf, topi);
  attn_flash<<<dim3(BH, NSPLIT), 256, 0, stream>>>(Qhg, Qlg, Khg, Klg, V, topi, pacc, pm, pl);
  base_kernel<<<DD / 16, 256, 0, stream>>>(Vsum, Wo, bo, base);
  fill_kernel<<<(NROWS * DD / 4) / 256, 256, 0, stream>>>(base, out);
  scatter_kernel<<<dim3(BH, UU), 256, 0, stream>>>(pacc, pm, pl, Vsum, topi, Wo, out);
}